// Round 8
// baseline (140.670 us; speedup 1.0000x reference)
//
#include <hip/hip_runtime.h>

// KnowledgeConsistentAttention: out = softmax_q( pool3x3(F) . K^T ) . K,  K = normalize(F+eps)
// pool3x3 acts only on the p index of S = F.K^T => flash-style fused kernel with
// Q=G=pool3x3(F), K=V=normalize(F+eps). exp(S) fits fp32 -> no max subtraction.
//
// R8 = R7 (K/V fragment images, linear DMA staging, 1 barrier/tile, packed P bounce)
// with M-per-wave doubled: rt=4 (64 p-rows/wave), 2-wave blocks (128p). Halves the
// per-CU LDS read traffic (the R7 bottleneck: 8.9MB -> 4.7MB @ 85B/cy) at the cost of
// ~450 VGPR -> 1 wave/SIMD. LDS pipe (~23us) then balances the MFMA pipe (~27us).

#define EPSV 1e-7f

typedef __bf16 bf16x8 __attribute__((ext_vector_type(8)));
typedef float f32x4 __attribute__((ext_vector_type(4)));
typedef unsigned short ushort8v __attribute__((ext_vector_type(8)));

__device__ __forceinline__ unsigned short f2bf(float f) {
    union { float f; unsigned int u; } x; x.f = f;
    unsigned int r = x.u + 0x7FFFu + ((x.u >> 16) & 1u);
    return (unsigned short)(r >> 16);
}

__device__ __forceinline__ f32x4 mfma16(bf16x8 a, bf16x8 b, f32x4 c) {
    return __builtin_amdgcn_mfma_f32_16x16x32_bf16(a, b, c, 0, 0, 0);
}

__device__ __forceinline__ void gload_lds16(const void* g, void* l) {
    __builtin_amdgcn_global_load_lds((const __attribute__((address_space(1))) void*)g,
                                     (__attribute__((address_space(3))) void*)l, 16, 0, 0);
}

// ---------------- prep 1: Khi2 (B-fragment image) + Vt2 (A-fragment image) ----------------
// Khi2: per (b, 32q-tile t, chunk = kg*2+ct): 1KB; lane L holds 16B = 8 bf16:
//   K[t*32 + ct*16 + (L&15)][kg*32 + (L>>4)*8 + e]   (16x16x32 B-operand layout)
// Vt2: per (b, 32q-tile t, c16): 1KB; lane L holds 16B:
//   V[q0 + slot(L>>4, e)][c16*16 + (L&15)], slot(g4,e) = g4*4 + (e>>1) + 16*(e&1).
__global__ __launch_bounds__(256) void prep_kv(const float* __restrict__ F,
                                               unsigned short* __restrict__ Khi2,
                                               unsigned short* __restrict__ Vt2) {
    __shared__ unsigned short ldsT[256 * 74];   // [c][64q], 148B rows (for V gather)
    __shared__ unsigned short ldsR[64 * 264];   // [qloc][c], 528B rows (for K frags)
    const int tid = threadIdx.x;
    const int w = tid >> 6, lane = tid & 63;
    const int q0 = blockIdx.x * 64;
    const int b = blockIdx.y;
    const size_t bq = (size_t)b * 4096;

    for (int r = 0; r < 16; ++r) {
        const int qloc = w * 16 + r;
        const int q = q0 + qloc;
        const float4 f = *(const float4*)(F + ((bq + q) << 8) + lane * 4);
        float v0 = f.x + EPSV, v1 = f.y + EPSV, v2 = f.z + EPSV, v3 = f.w + EPSV;
        float ss = v0 * v0 + v1 * v1 + v2 * v2 + v3 * v3;
        #pragma unroll
        for (int m = 1; m <= 32; m <<= 1) ss += __shfl_xor(ss, m);
        const float inv = 1.0f / sqrtf(ss);
        const unsigned short k0 = f2bf(v0 * inv), k1 = f2bf(v1 * inv);
        const unsigned short k2 = f2bf(v2 * inv), k3 = f2bf(v3 * inv);
        ushort4 kk; kk.x = k0; kk.y = k1; kk.z = k2; kk.w = k3;
        *(ushort4*)(ldsR + qloc * 264 + lane * 4) = kk;
        ldsT[(lane * 4 + 0) * 74 + qloc] = k0;
        ldsT[(lane * 4 + 1) * 74 + qloc] = k1;
        ldsT[(lane * 4 + 2) * 74 + qloc] = k2;
        ldsT[(lane * 4 + 3) * 74 + qloc] = k3;
    }
    __syncthreads();

    const size_t tbase = (size_t)b * 128 + (size_t)blockIdx.x * 2;

    // ---- K fragments from ldsR ----
    #pragma unroll
    for (int tsub = 0; tsub < 2; ++tsub) {
        char* dstK = (char*)Khi2 + ((tbase + tsub) << 14);
        #pragma unroll
        for (int i = 0; i < 4; ++i) {
            const int fi = i * 256 + tid;
            const int chunk = fi >> 6, L = fi & 63;
            const int l15 = L & 15, g4v = L >> 4;
            const int kg = chunk >> 1, ct = chunk & 1;
            const int qloc = tsub * 32 + ct * 16 + l15;
            const int c0 = kg * 32 + g4v * 8;
            *(ushort8v*)(dstK + fi * 16) = *(const ushort8v*)(ldsR + qloc * 264 + c0);
        }
    }

    // ---- V fragments from ldsT (sigma slot order) ----
    const int c = tid;
    const int c16v = c >> 4, l15c = c & 15;
    const unsigned short* row = ldsT + c * 74;
    #pragma unroll
    for (int tsub = 0; tsub < 2; ++tsub) {
        const unsigned short* qrow = row + tsub * 32;
        #pragma unroll
        for (int g4v = 0; g4v < 4; ++g4v) {
            ushort8v frag;
            #pragma unroll
            for (int e = 0; e < 8; ++e)
                frag[e] = qrow[(g4v * 4 + (e >> 1)) + ((e & 1) << 4)];  // sigma slots
            *(ushort8v*)((char*)Vt2 + ((tbase + tsub) << 14) + (c16v << 10) +
                         ((g4v * 16 + l15c) << 4)) = frag;
        }
    }
}

// ---------------- prep 2: G = pool3x3(F) * 9/cnt (TF SAME), separable, bf16 ----------------
__global__ __launch_bounds__(256) void prep_g(const float* __restrict__ F,
                                              unsigned short* __restrict__ G) {
    __shared__ float vs[64 * 256];
    const int tid = threadIdx.x;
    const int i = blockIdx.x, b = blockIdx.y;
    const size_t bq = (size_t)b * 4096;
    const int i0 = i > 0 ? i - 1 : 0, i1 = i < 63 ? i + 1 : 63;
    #pragma unroll
    for (int k2 = 0; k2 < 16; ++k2) {
        const int cell = k2 * 256 + tid;
        const int j = cell >> 6, c4 = (cell & 63) << 2;
        float4 acc = {0.f, 0.f, 0.f, 0.f};
        for (int ii = i0; ii <= i1; ++ii) {
            const float4 f = *(const float4*)(F + ((bq + ii * 64 + j) << 8) + c4);
            acc.x += f.x; acc.y += f.y; acc.z += f.z; acc.w += f.w;
        }
        *(float4*)(vs + j * 256 + c4) = acc;
    }
    __syncthreads();
    const float ri = (float)(i1 - i0 + 1);
    #pragma unroll
    for (int k2 = 0; k2 < 16; ++k2) {
        const int cell = k2 * 256 + tid;
        const int j = cell >> 6, c4 = (cell & 63) << 2;
        const int j0 = j > 0 ? j - 1 : 0, j1 = j < 63 ? j + 1 : 63;
        float4 s = {0.f, 0.f, 0.f, 0.f};
        for (int jj = j0; jj <= j1; ++jj) {
            const float4 v = *(const float4*)(vs + jj * 256 + c4);
            s.x += v.x; s.y += v.y; s.z += v.z; s.w += v.w;
        }
        const float scale = 9.0f / (ri * (float)(j1 - j0 + 1));
        ushort4 gv; gv.x = f2bf(s.x * scale); gv.y = f2bf(s.y * scale);
        gv.z = f2bf(s.z * scale); gv.w = f2bf(s.w * scale);
        *(ushort4*)(G + ((bq + i * 64 + j) << 8) + c4) = gv;
    }
}

// ---------------- main fused attention ----------------
// grid 512 (XCD-swizzled -> pb[32] x split[4] x b[4]), 128 threads (2 waves, 64p each).
// Per 32q tile: K + V fragment images DMA'd linearly to LDS double-buffers (issued a full
// tile ahead, drained by the single end-of-tile barrier). S = G@K^T (A=G regs, 64 mfma);
// exp -> packed-u32 P bounce per rt-quadrant (a2 read interleaved); O^T += V@P (64 mfma).
template <int ATOMIC>
__global__ __launch_bounds__(128, 1) void attn_main(
        const unsigned short* __restrict__ Khi2, const unsigned short* __restrict__ Vt2,
        const unsigned short* __restrict__ G, float* __restrict__ wsl,
        float* __restrict__ dOut, float* __restrict__ wsO) {
    __shared__ unsigned short ldsK[2][32 * 256];  // 2 x 16KB, linear fragment image
    __shared__ unsigned short ldsV[2][32 * 256];  // 2 x 16KB, linear fragment image
    __shared__ unsigned int ldsP[2][64 * 20];     // 10KB, per-wave P, 80B rows, sigma slots
    const int tid = threadIdx.x;
    const int w = tid >> 6, lane = tid & 63;
    const int l15 = lane & 15, g4 = lane >> 4;

    // XCD-aware decomposition: all 32 pb of a (split,b) group land on one XCD
    const int bid = blockIdx.x;
    const int u = bid & 7, v = bid >> 3;
    const int group = u * 2 + (v >> 5);
    const int pb = v & 31;
    const int split = group >> 2, b = group & 3;

    const int pw = pb * 128 + w * 64;   // wave owns 64 p-rows
    const size_t bq = (size_t)b * 4096;

    const char* KhiB = (const char*)Khi2 + (((size_t)b * 128 + split * 32) << 14);
    const char* VtB = (const char*)Vt2 + (((size_t)b * 128 + split * 32) << 14);

    // prologue: stage K(0) + V(0) (both linear copies) into buf 0
    #pragma unroll
    for (int it = 0; it < 8; ++it) {
        const int g = it * 128 + tid;
        gload_lds16(KhiB + g * 16, (char*)&ldsK[0][0] + g * 16);
    }
    #pragma unroll
    for (int it = 0; it < 8; ++it) {
        const int g = it * 128 + tid;
        gload_lds16(VtB + g * 16, (char*)&ldsV[0][0] + g * 16);
    }

    // preload G A-frags: 64 rows x 256 k per wave -> 128 VGPRs
    bf16x8 a[4][8];
    #pragma unroll
    for (int rt = 0; rt < 4; ++rt)
        #pragma unroll
        for (int kg = 0; kg < 8; ++kg)
            a[rt][kg] = *(const bf16x8*)(G + ((bq + pw + rt * 16 + l15) << 8) + (kg << 5) + (g4 << 3));

    f32x4 o[4][16];
    float lacc[4][4];
    #pragma unroll
    for (int rt = 0; rt < 4; ++rt) {
        #pragma unroll
        for (int c16 = 0; c16 < 16; ++c16) o[rt][c16] = f32x4{0.f, 0.f, 0.f, 0.f};
        #pragma unroll
        for (int r = 0; r < 4; ++r) lacc[rt][r] = 0.f;
    }
    unsigned int* Pw = &ldsP[w][0];

    __syncthreads();  // tile 0 landed

    #pragma unroll 1
    for (int t = 0; t < 32; ++t) {
        const int cur = t & 1;

        // issue stage of K(t+1)+V(t+1) (drained by end-of-iter barrier, a full tile away)
        if (t < 31) {
            const char* ks = KhiB + ((size_t)(t + 1) << 14);
            #pragma unroll
            for (int it = 0; it < 8; ++it) {
                const int g = it * 128 + tid;
                gload_lds16(ks + g * 16, (char*)&ldsK[cur ^ 1][0] + g * 16);
            }
            const char* vs2 = VtB + ((size_t)(t + 1) << 14);
            #pragma unroll
            for (int it = 0; it < 8; ++it) {
                const int g = it * 128 + tid;
                gload_lds16(vs2 + g * 16, (char*)&ldsV[cur ^ 1][0] + g * 16);
            }
        }

        // ---- GEMM1: S[64p x 32q]; B-frags = contiguous 1KB chunk reads ----
        f32x4 s[4][2];
        #pragma unroll
        for (int rt = 0; rt < 4; ++rt) {
            s[rt][0] = f32x4{0.f, 0.f, 0.f, 0.f};
            s[rt][1] = f32x4{0.f, 0.f, 0.f, 0.f};
        }
        const char* kb = (const char*)&ldsK[cur][0] + (lane << 4);
        __builtin_amdgcn_s_setprio(1);
        #pragma unroll
        for (int kg = 0; kg < 8; ++kg) {
            const bf16x8 bk0 = *(const bf16x8*)(kb + (kg * 2 + 0) * 1024);
            const bf16x8 bk1 = *(const bf16x8*)(kb + (kg * 2 + 1) * 1024);
            #pragma unroll
            for (int rt = 0; rt < 4; ++rt) {
                s[rt][0] = mfma16(a[rt][kg], bk0, s[rt][0]);
                s[rt][1] = mfma16(a[rt][kg], bk1, s[rt][1]);
            }
        }
        __builtin_amdgcn_s_setprio(0);

        // ---- exp + l accum + packed P writes; a2 read interleaved per rt-quadrant ----
        bf16x8 a2[4];
        #pragma unroll
        for (int rt = 0; rt < 4; ++rt) {
            #pragma unroll
            for (int r = 0; r < 4; ++r) {
                const float e0 = __expf(s[rt][0][r]);
                const float e1 = __expf(s[rt][1][r]);
                lacc[rt][r] += e0 + e1;
                union { __bf16 h[2]; unsigned int u; } pk;
                pk.h[0] = (__bf16)e0; pk.h[1] = (__bf16)e1;
                Pw[(rt * 16 + g4 * 4 + r) * 20 + l15] = pk.u;
            }
            a2[rt] = *(const bf16x8*)((const char*)Pw + (rt * 16 + l15) * 80 + (g4 << 4));
        }

        // ---- GEMM2 (O^T): A = V-frag (contiguous 1KB chunk), B = P-frag ----
        const char* vbase = (const char*)&ldsV[cur][0] + (lane << 4);
        __builtin_amdgcn_s_setprio(1);
        #pragma unroll
        for (int c16 = 0; c16 < 16; ++c16) {
            const bf16x8 bv = *(const bf16x8*)(vbase + c16 * 1024);
            #pragma unroll
            for (int rt = 0; rt < 4; ++rt)
                o[rt][c16] = mfma16(bv, a2[rt], o[rt][c16]);
        }
        __builtin_amdgcn_s_setprio(0);

        if (t < 31) __syncthreads();  // K/V(t+1) staged + buffer handoff
    }

    // ---- epilogue: reduce l across 16 q-columns ----
    #pragma unroll
    for (int rt = 0; rt < 4; ++rt)
        #pragma unroll
        for (int r = 0; r < 4; ++r) {
            float vsum = lacc[rt][r];
            #pragma unroll
            for (int m = 1; m <= 8; m <<= 1) vsum += __shfl_xor(vsum, m);
            lacc[rt][r] = vsum;
        }
    if (l15 == 0) {
        #pragma unroll
        for (int rt = 0; rt < 4; ++rt)
            #pragma unroll
            for (int r = 0; r < 4; ++r)
                wsl[(size_t)split * 16384 + bq + pw + rt * 16 + g4 * 4 + r] = lacc[rt][r];
    }

    // O^T D-layout: p = pw + rt*16 + l15, c = c16*16 + g4*4 + r -> float4 coalesced stores
    if (!ATOMIC) {
        float* dst = (split == 0) ? dOut : (wsO + (size_t)(split - 1) * 4194304);
        #pragma unroll
        for (int rt = 0; rt < 4; ++rt)
            #pragma unroll
            for (int c16 = 0; c16 < 16; ++c16)
                *(f32x4*)(dst + ((bq + pw + rt * 16 + l15) << 8) + c16 * 16 + (g4 << 2)) = o[rt][c16];
    } else {
        #pragma unroll
        for (int rt = 0; rt < 4; ++rt)
            #pragma unroll
            for (int c16 = 0; c16 < 16; ++c16)
                #pragma unroll
                for (int r = 0; r < 4; ++r) {
                    const size_t idx = ((bq + pw + rt * 16 + l15) << 8) + c16 * 16 + (g4 << 2) + r;
                    atomicAdd(&dOut[idx], o[rt][c16][r]);
                }
    }
}

// ---------------- finalize: sum q-split partials, divide by l ----------------
__global__ __launch_bounds__(256) void reduce_fin(float* __restrict__ dOut,
                                                  const float* __restrict__ wsO,
                                                  const float* __restrict__ wsl) {
    const int i4 = blockIdx.x * 256 + threadIdx.x;
    const int row = i4 >> 6;
    const float l = wsl[row] + wsl[16384 + row] + wsl[32768 + row] + wsl[49152 + row];
    const float inv = 1.0f / l;
    float4 v = ((const float4*)dOut)[i4];
    const float4 a = ((const float4*)wsO)[i4];
    const float4 b = ((const float4*)(wsO + 4194304))[i4];
    const float4 c = ((const float4*)(wsO + 8388608))[i4];
    v.x = (v.x + a.x + b.x + c.x) * inv;
    v.y = (v.y + a.y + b.y + c.y) * inv;
    v.z = (v.z + a.z + b.z + c.z) * inv;
    v.w = (v.w + a.w + b.w + c.w) * inv;
    ((float4*)dOut)[i4] = v;
}

__global__ __launch_bounds__(256) void divide_fin(float* __restrict__ dOut,
                                                  const float* __restrict__ wsl) {
    const int i4 = blockIdx.x * 256 + threadIdx.x;
    const int row = i4 >> 6;
    const float l = wsl[row] + wsl[16384 + row] + wsl[32768 + row] + wsl[49152 + row];
    const float inv = 1.0f / l;
    float4 v = ((const float4*)dOut)[i4];
    v.x *= inv; v.y *= inv; v.z *= inv; v.w *= inv;
    ((float4*)dOut)[i4] = v;
}

extern "C" void kernel_launch(void* const* d_in, const int* in_sizes, int n_in,
                              void* d_out, int out_size, void* d_ws, size_t ws_size,
                              hipStream_t stream) {
    const float* F = (const float*)d_in[0];
    // d_in[1] (masks) has no effect on the output.
    float* out = (float*)d_out;
    char* ws = (char*)d_ws;

    // ws layout: Khi2 bf16 frag image (8MB) @0 | Vt2 bf16 frag image (8MB) @8MB |
    //            G bf16 [4][4096][256] @16MB | wsl f32 [4][16384] @24MB (256KB) |
    //            wsO f32 3x[4][4096][256] @24.25MB (48MB)
    unsigned short* Khi2 = (unsigned short*)ws;
    unsigned short* Vt2 = Khi2 + 4194304;
    unsigned short* G = Vt2 + 4194304;
    float* wsl = (float*)(ws + 25165824);
    float* wsO = (float*)(ws + 25165824 + 262144);
    const size_t needA = 25165824u + 262144u + 3u * 16777216u;

    prep_kv<<<dim3(64, 4), 256, 0, stream>>>(F, Khi2, Vt2);
    prep_g<<<dim3(64, 4), 256, 0, stream>>>(F, G);

    if (ws_size >= needA) {
        attn_main<0><<<dim3(512), 128, 0, stream>>>(Khi2, Vt2, G, wsl, out, wsO);
        reduce_fin<<<4096, 256, 0, stream>>>(out, wsO, wsl);
    } else {
        hipMemsetAsync(out, 0, 16777216, stream);
        attn_main<1><<<dim3(512), 128, 0, stream>>>(Khi2, Vt2, G, wsl, out, nullptr);
        divide_fin<<<4096, 256, 0, stream>>>(out, wsl);
    }
}